// Round 5
// baseline (1409.625 us; speedup 1.0000x reference)
//
#include <hip/hip_runtime.h>
#include <stdint.h>

#define DD 512
#define NB 25        // column buckets: col >> 11, 50000 -> 0..24
#define BSH 11

typedef __bf16 bf16x8 __attribute__((ext_vector_type(8)));
typedef float f32x4 __attribute__((ext_vector_type(4)));

__device__ __forceinline__ unsigned short f2bf(float f) {
  uint32_t u = __builtin_bit_cast(uint32_t, f);
  u += 0x7fff + ((u >> 16) & 1);  // RNE
  return (unsigned short)(u >> 16);
}
__device__ __forceinline__ float bfbits2f(uint32_t lo16) {
  return __builtin_bit_cast(float, lo16 << 16);
}

// ---------------- CSR build (column-bucketed) ----------------
// Edges are stored per-row in column-BUCKET-sorted order (bucket = col>>11).
// All resident blocks then sweep the same ascending column window together,
// so the gather working set is a few MB instead of all 51 MB of H
// (round-3 counters: ~700 MB/dispatch of H re-fetch = L3 thrash; round-1
// proved locality removes it, FETCH 828->316 MB).
__global__ void hist2_kernel(const int* __restrict__ rows, const int* __restrict__ cols,
                             int* __restrict__ counts2, int E) {
  int i = blockIdx.x * blockDim.x + threadIdx.x;
  if (i < E) {
    int r = rows[i];
    int b = cols[i] >> BSH;
    atomicAdd(&counts2[r * NB + b], 1);
  }
}

// rowcnt[r] = sum over buckets
__global__ __launch_bounds__(256) void rowsum_kernel(const int* __restrict__ counts2,
                                                     int* __restrict__ rowcnt, int n) {
  int r = blockIdx.x * 256 + threadIdx.x;
  if (r >= n) return;
  int s = 0;
#pragma unroll
  for (int b = 0; b < NB; ++b) s += counts2[r * NB + b];
  rowcnt[r] = s;
}

// NOTE: rounds each row's count up to a multiple of 8 (pad slots are pre-zeroed
// col=0/val=0 edges -> contribute exactly 0, keep the edge loop tail-free).
__global__ __launch_bounds__(256) void scan_block(const int* __restrict__ counts,
                                                  int* __restrict__ offs, int* __restrict__ bsum,
                                                  int n) {
  __shared__ int sm[256];
  int t = threadIdx.x;
  int i = blockIdx.x * 256 + t;
  int v = (i < n) ? ((counts[i] + 7) & ~7) : 0;
  sm[t] = v;
  __syncthreads();
  for (int o = 1; o < 256; o <<= 1) {
    int x = (t >= o) ? sm[t - o] : 0;
    __syncthreads();
    sm[t] += x;
    __syncthreads();
  }
  if (i < n) offs[i + 1] = sm[t];
  if (t == 255) bsum[blockIdx.x] = sm[255];
}

__global__ __launch_bounds__(256) void scan_tops(int* __restrict__ bsum, int nb) {
  __shared__ int sm[256];
  int t = threadIdx.x;
  int v = (t < nb) ? bsum[t] : 0;
  sm[t] = v;
  __syncthreads();
  for (int o = 1; o < 256; o <<= 1) {
    int x = (t >= o) ? sm[t - o] : 0;
    __syncthreads();
    sm[t] += x;
    __syncthreads();
  }
  if (t < nb) bsum[t] = sm[t];
}

__global__ __launch_bounds__(256) void scan_add(int* __restrict__ offs,
                                                const int* __restrict__ bsum, int n) {
  int i = blockIdx.x * 256 + threadIdx.x;
  int add = (blockIdx.x > 0) ? bsum[blockIdx.x - 1] : 0;
  if (i < n) offs[i + 1] += add;
  if (i == 0) offs[0] = 0;
}

// per-row bucket base offsets (exclusive scan of counts2 within the row,
// based at offs[r]; pads land after the last bucket)
__global__ __launch_bounds__(256) void bucketoff_kernel(const int* __restrict__ offs,
                                                        const int* __restrict__ counts2,
                                                        int* __restrict__ boff, int n) {
  int r = blockIdx.x * 256 + threadIdx.x;
  if (r >= n) return;
  int run = offs[r];
#pragma unroll
  for (int b = 0; b < NB; ++b) {
    boff[r * NB + b] = run;
    run += counts2[r * NB + b];
  }
}

__global__ void scatter2_kernel(const int* __restrict__ rows, const int* __restrict__ colsIn,
                                const float* __restrict__ valsIn,
                                const int* __restrict__ boff, int* __restrict__ cursor,
                                int* __restrict__ colsC, unsigned short* __restrict__ valsC,
                                int E) {
  int i = blockIdx.x * blockDim.x + threadIdx.x;
  if (i < E) {
    int r = rows[i];
    int c = colsIn[i];
    int b = c >> BSH;
    int p = boff[r * NB + b] + atomicAdd(&cursor[r * NB + b], 1);
    colsC[p] = c;
    valsC[p] = f2bf(valsIn[i]);
  }
}

// ---------------- conversions ----------------
// x = A1[:,1:] (lda=513, +1 offset, unaligned) -> Xb bf16 [N][512]
__global__ __launch_bounds__(256) void convert_x(const float* __restrict__ A1,
                                                 __bf16* __restrict__ Xb, int N) {
  int id = blockIdx.x * 256 + threadIdx.x;  // one per 8 elements
  int total = (N * DD) >> 3;
  if (id >= total) return;
  int r = id >> 6;
  int c = (id & 63) * 8;
  const float* p = A1 + (size_t)r * 513 + 1 + c;
  unsigned short h[8];
#pragma unroll
  for (int k = 0; k < 8; ++k) h[k] = f2bf(p[k]);
  uint4 o;
  o.x = (uint32_t)h[0] | ((uint32_t)h[1] << 16);
  o.y = (uint32_t)h[2] | ((uint32_t)h[3] << 16);
  o.z = (uint32_t)h[4] | ((uint32_t)h[5] << 16);
  o.w = (uint32_t)h[6] | ((uint32_t)h[7] << 16);
  *(uint4*)(Xb + (size_t)r * DD + c) = o;
}

// W fp32 [k][n] -> Wt bf16 [n][k]  (transpose + convert)
__global__ __launch_bounds__(256) void convert_wt(const float* __restrict__ W,
                                                  __bf16* __restrict__ Wt) {
  __shared__ float tile[32][33];
  int bx = blockIdx.x * 32;  // n base
  int by = blockIdx.y * 32;  // k base
  int tx = threadIdx.x & 31, ty = threadIdx.x >> 5;  // ty 0..7
#pragma unroll
  for (int q = 0; q < 4; ++q)
    tile[ty + q * 8][tx] = W[(size_t)(by + ty + q * 8) * DD + bx + tx];
  __syncthreads();
  unsigned short* Wts = (unsigned short*)Wt;
#pragma unroll
  for (int q = 0; q < 4; ++q)
    Wts[(size_t)(bx + ty + q * 8) * DD + by + tx] = f2bf(tile[tx][ty + q * 8]);
}

// ---------------- MFMA GEMM: C[M x 512] = A[M x 512] * B + bias ----------------
// A bf16 [M][512]; Bt bf16 [n][k] (transposed weights).
// 128x128 tile, 256 thr = 4 waves (2x2 of 64x64), BK=64, mfma_f32_16x16x32_bf16.
// Staging via global_load_lds width=16 into LINEAR LDS [128][64].
// MODE 0: a0 = acc+bias -> out[r*1024+512+c] (fp32); a1 = a0*n[r] -> out[r*1024+c]
// MODE 1: Yb[r*512+c] = bf16(acc + bias[c])
template <int MODE>
__global__ __launch_bounds__(256) void gemm_mfma(
    const __bf16* __restrict__ A,
    const __bf16* __restrict__ Bt,
    const float* __restrict__ bias,
    __bf16* __restrict__ Yb,
    float* __restrict__ out,
    const float* __restrict__ nvec,
    int M) {
  __shared__ __bf16 As[128][64];  // linear: 128B row stride (gld_lds dest)
  __shared__ __bf16 Bs[128][64];
  const int tid = threadIdx.x;
  const int bx = blockIdx.x >> 2;       // M-panel
  const int by = blockIdx.x & 3;        // N-panel (innermost -> A-panel reuse)
  const int bm = bx * 128;
  const int bn = by * 128;
  const int lane = tid & 63;
  const int w = tid >> 6;
  const int wm = (w & 1) * 64;
  const int wn = (w >> 1) * 64;
  const int m16 = lane & 15;
  const int quad = lane >> 4;

  f32x4 acc[4][4];
#pragma unroll
  for (int i = 0; i < 4; ++i)
#pragma unroll
    for (int j = 0; j < 4; ++j) acc[i][j] = (f32x4){0.f, 0.f, 0.f, 0.f};

  const int soff = tid * 16;            // byte offset within 4KB chunk
  const int srow_base = soff >> 7;      // row contribution (rows advance 32/chunk)
  const int skb = soff & 127;           // byte within 128B row

  for (int k0 = 0; k0 < DD; k0 += 64) {
#pragma unroll
    for (int q = 0; q < 4; ++q) {
      int row = q * 32 + srow_base;
      int gm = bm + row;
      if (gm >= M) gm = M - 1;  // clamp (stores guarded)
      const char* ga = (const char*)A + ((size_t)gm * DD + k0) * 2 + skb;
      char* la = (char*)&As[0][0] + q * 4096 + w * 1024;  // wave-uniform
      __builtin_amdgcn_global_load_lds(
          (const __attribute__((address_space(1))) void*)ga,
          (__attribute__((address_space(3))) void*)la, 16, 0, 0);
      const char* gb = (const char*)Bt + ((size_t)(bn + row) * DD + k0) * 2 + skb;
      char* lb = (char*)&Bs[0][0] + q * 4096 + w * 1024;  // wave-uniform
      __builtin_amdgcn_global_load_lds(
          (const __attribute__((address_space(1))) void*)gb,
          (__attribute__((address_space(3))) void*)lb, 16, 0, 0);
    }
    __syncthreads();
#pragma unroll
    for (int ks = 0; ks < 2; ++ks) {
      int kb = ks * 32 + quad * 8;
      bf16x8 af[4], bf[4];
#pragma unroll
      for (int i = 0; i < 4; ++i) af[i] = *(const bf16x8*)&As[wm + i * 16 + m16][kb];
#pragma unroll
      for (int j = 0; j < 4; ++j) bf[j] = *(const bf16x8*)&Bs[wn + j * 16 + m16][kb];
#pragma unroll
      for (int i = 0; i < 4; ++i)
#pragma unroll
        for (int j = 0; j < 4; ++j)
          acc[i][j] = __builtin_amdgcn_mfma_f32_16x16x32_bf16(af[i], bf[j], acc[i][j], 0, 0, 0);
    }
    __syncthreads();
  }

  float bv[4];
#pragma unroll
  for (int j = 0; j < 4; ++j) bv[j] = bias[bn + wn + j * 16 + m16];

  unsigned short* Ybs = (unsigned short*)Yb;
#pragma unroll
  for (int i = 0; i < 4; ++i) {
#pragma unroll
    for (int r = 0; r < 4; ++r) {
      int row = bm + wm + i * 16 + quad * 4 + r;
      if (row < M) {
        if (MODE == 0) {
          float nv = nvec[row];
#pragma unroll
          for (int j = 0; j < 4; ++j) {
            int c = bn + wn + j * 16 + m16;
            float a0 = acc[i][j][r] + bv[j];
            out[(size_t)row * 1024 + 512 + c] = a0;
            out[(size_t)row * 1024 + c] = a0 * nv;
          }
        } else {
#pragma unroll
          for (int j = 0; j < 4; ++j) {
            int c = bn + wn + j * 16 + m16;
            Ybs[(size_t)row * DD + c] = f2bf(acc[i][j][r] + bv[j]);
          }
        }
      }
    }
  }
}

// ---------------- SpMM (CSR padded to x8, column-bucket-sorted edges) ----------------
// 256 thr = 4 row-groups x 64 lanes; lane owns dims [8l, 8l+8) -> one 16B uint4
// gather per edge (64 lanes x 16B = full 1KB row). Edge loop: exact 8-edge unroll.
// Edges ascend by column bucket, so concurrent blocks sweep the same column
// window -> H stays cache-resident instead of thrashing (see CSR build note).
// MODE 0: Xb[r*512+d..] = bf16(acc)
// MODE 1: Xb[r*512+d..] = bf16(a1[r*1024+d..] + acc*(1-n[r]))
// MODE 2: outF[r*1024+d..] = acc (fp32)
template <int MODE>
__global__ __launch_bounds__(256) void spmm_bf16(
    const int* __restrict__ offs, const int* __restrict__ cols,
    const unsigned short* __restrict__ vals,
    const __bf16* __restrict__ H,
    __bf16* __restrict__ Xb, float* __restrict__ outF,
    const float* __restrict__ a1, const float* __restrict__ nvec, int N) {
  int rg = threadIdx.x >> 6;
  int lane = threadIdx.x & 63;
  int r = blockIdx.x * 4 + rg;
  if (r >= N) return;
  int d = lane * 8;
  const unsigned short* Hp = (const unsigned short*)H + d;
  int s = offs[r], e = offs[r + 1];

  float ac[8];
#pragma unroll
  for (int k = 0; k < 8; ++k) ac[k] = 0.f;

  for (int i = s; i < e; i += 8) {
    int4 ca = *(const int4*)(cols + i);
    int4 cb = *(const int4*)(cols + i + 4);
    uint4 vw = *(const uint4*)(vals + i);  // 8 bf16 vals
    uint4 h[8];
    h[0] = *(const uint4*)(Hp + (size_t)ca.x * DD);
    h[1] = *(const uint4*)(Hp + (size_t)ca.y * DD);
    h[2] = *(const uint4*)(Hp + (size_t)ca.z * DD);
    h[3] = *(const uint4*)(Hp + (size_t)ca.w * DD);
    h[4] = *(const uint4*)(Hp + (size_t)cb.x * DD);
    h[5] = *(const uint4*)(Hp + (size_t)cb.y * DD);
    h[6] = *(const uint4*)(Hp + (size_t)cb.z * DD);
    h[7] = *(const uint4*)(Hp + (size_t)cb.w * DD);
    float v[8];
    v[0] = bfbits2f(vw.x & 0xffffu);
    v[1] = bfbits2f(vw.x >> 16);
    v[2] = bfbits2f(vw.y & 0xffffu);
    v[3] = bfbits2f(vw.y >> 16);
    v[4] = bfbits2f(vw.z & 0xffffu);
    v[5] = bfbits2f(vw.z >> 16);
    v[6] = bfbits2f(vw.w & 0xffffu);
    v[7] = bfbits2f(vw.w >> 16);
#pragma unroll
    for (int k = 0; k < 8; ++k) {
      ac[0] += v[k] * bfbits2f(h[k].x & 0xffffu);
      ac[1] += v[k] * bfbits2f(h[k].x >> 16);
      ac[2] += v[k] * bfbits2f(h[k].y & 0xffffu);
      ac[3] += v[k] * bfbits2f(h[k].y >> 16);
      ac[4] += v[k] * bfbits2f(h[k].z & 0xffffu);
      ac[5] += v[k] * bfbits2f(h[k].z >> 16);
      ac[6] += v[k] * bfbits2f(h[k].w & 0xffffu);
      ac[7] += v[k] * bfbits2f(h[k].w >> 16);
    }
  }

  if (MODE == 2) {
    float4 o0, o1;
    o0.x = ac[0]; o0.y = ac[1]; o0.z = ac[2]; o0.w = ac[3];
    o1.x = ac[4]; o1.y = ac[5]; o1.z = ac[6]; o1.w = ac[7];
    *(float4*)(outF + (size_t)r * 1024 + d) = o0;
    *(float4*)(outF + (size_t)r * 1024 + d + 4) = o1;
  } else {
    if (MODE == 1) {
      float g = 1.f - nvec[r];
      float4 a0 = *(const float4*)(a1 + (size_t)r * 1024 + d);
      float4 a1v = *(const float4*)(a1 + (size_t)r * 1024 + d + 4);
      ac[0] = a0.x + ac[0] * g;
      ac[1] = a0.y + ac[1] * g;
      ac[2] = a0.z + ac[2] * g;
      ac[3] = a0.w + ac[3] * g;
      ac[4] = a1v.x + ac[4] * g;
      ac[5] = a1v.y + ac[5] * g;
      ac[6] = a1v.z + ac[6] * g;
      ac[7] = a1v.w + ac[7] * g;
    }
    uint4 p;
    p.x = ((uint32_t)f2bf(ac[1]) << 16) | (uint32_t)f2bf(ac[0]);
    p.y = ((uint32_t)f2bf(ac[3]) << 16) | (uint32_t)f2bf(ac[2]);
    p.z = ((uint32_t)f2bf(ac[5]) << 16) | (uint32_t)f2bf(ac[4]);
    p.w = ((uint32_t)f2bf(ac[7]) << 16) | (uint32_t)f2bf(ac[6]);
    *(uint4*)((unsigned short*)Xb + (size_t)r * DD + d) = p;
  }
}

extern "C" void kernel_launch(void* const* d_in, const int* in_sizes, int n_in,
                              void* d_out, int out_size, void* d_ws, size_t ws_size,
                              hipStream_t stream) {
  const float* A1       = (const float*)d_in[0];
  const int*   adj_rows = (const int*)d_in[1];
  const int*   adj_cols = (const int*)d_in[2];
  const float* adj_vals = (const float*)d_in[3];
  const float* Lin1     = (const float*)d_in[4];
  const float* Lin1b    = (const float*)d_in[5];
  const float* nvec     = (const float*)d_in[6];
  const float* W1       = (const float*)d_in[7];
  const float* b1       = (const float*)d_in[8];
  const float* W2       = (const float*)d_in[9];
  const float* b2       = (const float*)d_in[10];
  const float* W3       = (const float*)d_in[11];
  const float* b3       = (const float*)d_in[12];
  const int N = in_sizes[6];
  const int E = in_sizes[1];
  float* out = (float*)d_out;

  uint8_t* base = (uint8_t*)d_ws;
  size_t off = 0;
  auto take = [&](size_t bytes) -> void* {
    off = (off + 255) & ~(size_t)255;
    void* r = base + off;
    off += bytes;
    return r;
  };
  const size_t EP = (size_t)E + 8 * (size_t)N;              // padded edge bound
  __bf16* Xb     = (__bf16*)take((size_t)N * DD * 2);       // 51.2 MB (x -> x1 -> s2)
  __bf16* Yb     = (__bf16*)take((size_t)N * DD * 2);       // 51.2 MB (GEMM outs)
  __bf16* Wt     = (__bf16*)take((size_t)4 * DD * DD * 2);  // 2 MB (transposed weights)
  int*    colsC  = (int*)take(EP * sizeof(int));
  unsigned short* valsC = (unsigned short*)take(EP * 2);
  int*    offs   = (int*)take((size_t)(N + 1) * sizeof(int));
  int*    counts2= (int*)take((size_t)N * NB * sizeof(int)); // 5 MB (hist, then cursor)
  int*    boff   = (int*)take((size_t)N * NB * sizeof(int)); // 5 MB bucket offsets
  int*    rowcnt = (int*)take((size_t)N * sizeof(int));
  int*    bsum   = (int*)take(1024);
  (void)ws_size; (void)n_in; (void)out_size;

  __bf16* Wt0 = Wt;
  __bf16* Wt1 = Wt + (size_t)DD * DD;
  __bf16* Wt2 = Wt + (size_t)2 * DD * DD;
  __bf16* Wt3 = Wt + (size_t)3 * DD * DD;

  int eb = (E + 255) / 256;
  int nb = (N + 255) / 256;

  // CSR build, column-bucketed (rows padded to x8; pads stay col=0/val=0)
  hipMemsetAsync(counts2, 0, (size_t)N * NB * sizeof(int), stream);
  hipMemsetAsync(colsC, 0, EP * sizeof(int), stream);
  hipMemsetAsync(valsC, 0, EP * 2, stream);
  hist2_kernel<<<eb, 256, 0, stream>>>(adj_rows, adj_cols, counts2, E);
  rowsum_kernel<<<nb, 256, 0, stream>>>(counts2, rowcnt, N);
  scan_block<<<nb, 256, 0, stream>>>(rowcnt, offs, bsum, N);
  scan_tops<<<1, 256, 0, stream>>>(bsum, nb);
  scan_add<<<nb, 256, 0, stream>>>(offs, bsum, N);
  bucketoff_kernel<<<nb, 256, 0, stream>>>(offs, counts2, boff, N);
  hipMemsetAsync(counts2, 0, (size_t)N * NB * sizeof(int), stream);  // cursor
  scatter2_kernel<<<eb, 256, 0, stream>>>(adj_rows, adj_cols, adj_vals, boff, counts2,
                                          colsC, valsC, E);

  // conversions
  convert_x<<<(N * DD / 8 + 255) / 256, 256, 0, stream>>>(A1, Xb, N);
  dim3 wgrid(16, 16);
  convert_wt<<<wgrid, 256, 0, stream>>>(Lin1, Wt0);
  convert_wt<<<wgrid, 256, 0, stream>>>(W1, Wt1);
  convert_wt<<<wgrid, 256, 0, stream>>>(W2, Wt2);
  convert_wt<<<wgrid, 256, 0, stream>>>(W3, Wt3);

  int ggrid = ((N + 127) / 128) * 4;  // 1D, 4 N-panels innermost
  int sgrid = (N + 3) / 4;            // 4 rows per block

  // GEMM0: a0 -> out[:,512:] fp32; a1 = a0*n -> out[:,0:512] fp32
  gemm_mfma<0><<<ggrid, 256, 0, stream>>>(Xb, Wt0, Lin1b, nullptr, out, nvec, N);
  // GEMM1: y1 -> Yb
  gemm_mfma<1><<<ggrid, 256, 0, stream>>>(Xb, Wt1, b1, Yb, nullptr, nullptr, N);
  // SpMM1: x1 = a1 + spmm(y1)*(1-n) -> Xb (bf16)
  spmm_bf16<1><<<sgrid, 256, 0, stream>>>(offs, colsC, valsC, Yb, Xb, nullptr, out, nvec, N);
  // GEMM2: y2 -> Yb
  gemm_mfma<1><<<ggrid, 256, 0, stream>>>(Xb, Wt2, b2, Yb, nullptr, nullptr, N);
  // SpMM2: s2 -> Xb (bf16)
  spmm_bf16<0><<<sgrid, 256, 0, stream>>>(offs, colsC, valsC, Yb, Xb, nullptr, nullptr, nullptr, N);
  // GEMM3: y3 -> Yb
  gemm_mfma<1><<<ggrid, 256, 0, stream>>>(Xb, Wt3, b3, Yb, nullptr, nullptr, N);
  // SpMM3: x2 -> out[:,0:512] fp32
  spmm_bf16<2><<<sgrid, 256, 0, stream>>>(offs, colsC, valsC, Yb, nullptr, out, nullptr, nullptr, N);
}

// Round 6
// 1363.369 us; speedup vs baseline: 1.0339x; 1.0339x over previous
//
#include <hip/hip_runtime.h>
#include <stdint.h>

#define DD 512

typedef __bf16 bf16x8 __attribute__((ext_vector_type(8)));
typedef float f32x4 __attribute__((ext_vector_type(4)));

__device__ __forceinline__ unsigned short f2bf(float f) {
  uint32_t u = __builtin_bit_cast(uint32_t, f);
  u += 0x7fff + ((u >> 16) & 1);  // RNE
  return (unsigned short)(u >> 16);
}
__device__ __forceinline__ float bfbits2f(uint32_t lo16) {
  return __builtin_bit_cast(float, lo16 << 16);
}

// ---------------- CSR build ----------------
__global__ void hist_kernel(const int* __restrict__ rows, int* __restrict__ counts, int E) {
  int i = blockIdx.x * blockDim.x + threadIdx.x;
  if (i < E) atomicAdd(&counts[rows[i]], 1);
}

__global__ __launch_bounds__(256) void scan_block(const int* __restrict__ counts,
                                                  int* __restrict__ offs, int* __restrict__ bsum,
                                                  int n) {
  __shared__ int sm[256];
  int t = threadIdx.x;
  int i = blockIdx.x * 256 + t;
  int v = (i < n) ? counts[i] : 0;
  sm[t] = v;
  __syncthreads();
  for (int o = 1; o < 256; o <<= 1) {
    int x = (t >= o) ? sm[t - o] : 0;
    __syncthreads();
    sm[t] += x;
    __syncthreads();
  }
  if (i < n) offs[i + 1] = sm[t];
  if (t == 255) bsum[blockIdx.x] = sm[255];
}

__global__ __launch_bounds__(256) void scan_tops(int* __restrict__ bsum, int nb) {
  __shared__ int sm[256];
  int t = threadIdx.x;
  int v = (t < nb) ? bsum[t] : 0;
  sm[t] = v;
  __syncthreads();
  for (int o = 1; o < 256; o <<= 1) {
    int x = (t >= o) ? sm[t - o] : 0;
    __syncthreads();
    sm[t] += x;
    __syncthreads();
  }
  if (t < nb) bsum[t] = sm[t];
}

__global__ __launch_bounds__(256) void scan_add(int* __restrict__ offs,
                                                const int* __restrict__ bsum, int n) {
  int i = blockIdx.x * 256 + threadIdx.x;
  int add = (blockIdx.x > 0) ? bsum[blockIdx.x - 1] : 0;
  if (i < n) offs[i + 1] += add;
  if (i == 0) offs[0] = 0;
}

__global__ void scatter_kernel(const int* __restrict__ rows, const int* __restrict__ colsIn,
                               const float* __restrict__ valsIn, const int* __restrict__ offs,
                               int* __restrict__ cursor, int* __restrict__ colsC,
                               unsigned short* __restrict__ valsC, int E) {
  int i = blockIdx.x * blockDim.x + threadIdx.x;
  if (i < E) {
    int r = rows[i];
    int p = offs[r] + atomicAdd(&cursor[r], 1);
    colsC[p] = colsIn[i];
    valsC[p] = f2bf(valsIn[i]);
  }
}

// ---------------- conversions ----------------
// x = A1[:,1:] (lda=513, +1 offset, unaligned) -> Xb bf16 [N][512]
__global__ __launch_bounds__(256) void convert_x(const float* __restrict__ A1,
                                                 __bf16* __restrict__ Xb, int N) {
  int id = blockIdx.x * 256 + threadIdx.x;  // one per 8 elements
  int total = (N * DD) >> 3;
  if (id >= total) return;
  int r = id >> 6;
  int c = (id & 63) * 8;
  const float* p = A1 + (size_t)r * 513 + 1 + c;
  unsigned short h[8];
#pragma unroll
  for (int k = 0; k < 8; ++k) h[k] = f2bf(p[k]);
  uint4 o;
  o.x = (uint32_t)h[0] | ((uint32_t)h[1] << 16);
  o.y = (uint32_t)h[2] | ((uint32_t)h[3] << 16);
  o.z = (uint32_t)h[4] | ((uint32_t)h[5] << 16);
  o.w = (uint32_t)h[6] | ((uint32_t)h[7] << 16);
  *(uint4*)(Xb + (size_t)r * DD + c) = o;
}

// W fp32 [k][n] -> Wt bf16 [n][k]  (transpose + convert)
__global__ __launch_bounds__(256) void convert_wt(const float* __restrict__ W,
                                                  __bf16* __restrict__ Wt) {
  __shared__ float tile[32][33];
  int bx = blockIdx.x * 32;  // n base
  int by = blockIdx.y * 32;  // k base
  int tx = threadIdx.x & 31, ty = threadIdx.x >> 5;  // ty 0..7
#pragma unroll
  for (int q = 0; q < 4; ++q)
    tile[ty + q * 8][tx] = W[(size_t)(by + ty + q * 8) * DD + bx + tx];
  __syncthreads();
  unsigned short* Wts = (unsigned short*)Wt;
#pragma unroll
  for (int q = 0; q < 4; ++q)
    Wts[(size_t)(bx + ty + q * 8) * DD + by + tx] = f2bf(tile[tx][ty + q * 8]);
}

// ---------------- MFMA GEMM: C[M x 512] = A[M x 512] * B + bias ----------------
// A bf16 [M][512]; Bt bf16 [n][k] (transposed weights).
// 128x128 tile, 256 thr = 4 waves (2x2 of 64x64), BK=64, mfma_f32_16x16x32_bf16.
// DOUBLE-BUFFERED prefetch (T3 minimum 2-phase): STAGE(t+1) is issued BEFORE
// compute(t); the single __syncthreads per step (compiler emits the vmcnt drain
// there) then lands AFTER ~400cy of MFMA+ds_read instead of after zero, hiding
// the staging latency that made the old stage->sync->compute->sync structure
// ~160us/GEMM (10x over both the 11us MFMA and ~35us memory floors).
// LDS = 2*(16KB+16KB) = 64KB -> 2 blocks/CU; latency hiding is intra-block now.
// MODE 0: a0 = acc+bias -> out[r*1024+512+c] (fp32); a1 = a0*n[r] -> out[r*1024+c]
// MODE 1: Yb[r*512+c] = bf16(acc + bias[c])
template <int MODE>
__global__ __launch_bounds__(256) void gemm_mfma(
    const __bf16* __restrict__ A,
    const __bf16* __restrict__ Bt,
    const float* __restrict__ bias,
    __bf16* __restrict__ Yb,
    float* __restrict__ out,
    const float* __restrict__ nvec,
    int M) {
  __shared__ __bf16 As[2][128][64];  // linear: 128B row stride (gld_lds dest)
  __shared__ __bf16 Bs[2][128][64];
  const int tid = threadIdx.x;
  const int bx = blockIdx.x >> 2;       // M-panel
  const int by = blockIdx.x & 3;        // N-panel (innermost -> A-panel reuse)
  const int bm = bx * 128;
  const int bn = by * 128;
  const int lane = tid & 63;
  const int w = tid >> 6;
  const int wm = (w & 1) * 64;
  const int wn = (w >> 1) * 64;
  const int m16 = lane & 15;
  const int quad = lane >> 4;

  f32x4 acc[4][4];
#pragma unroll
  for (int i = 0; i < 4; ++i)
#pragma unroll
    for (int j = 0; j < 4; ++j) acc[i][j] = (f32x4){0.f, 0.f, 0.f, 0.f};

  // staging geometry: thread t stages LDS bytes [t*16, t*16+16) of each 4KB
  // chunk; LDS dest is the wave-uniform base (HW adds lane*16).
  const int soff = tid * 16;
  const int srow_base = soff >> 7;      // row within 32-row chunk
  const int skb = soff & 127;           // byte within 128B row

  auto STAGE = [&](int buf, int k0) {
#pragma unroll
    for (int q = 0; q < 4; ++q) {
      int row = q * 32 + srow_base;
      int gm = bm + row;
      if (gm >= M) gm = M - 1;  // clamp (stores guarded)
      const char* ga = (const char*)A + ((size_t)gm * DD + k0) * 2 + skb;
      char* la = (char*)&As[buf][0][0] + q * 4096 + w * 1024;  // wave-uniform
      __builtin_amdgcn_global_load_lds(
          (const __attribute__((address_space(1))) void*)ga,
          (__attribute__((address_space(3))) void*)la, 16, 0, 0);
      const char* gb = (const char*)Bt + ((size_t)(bn + row) * DD + k0) * 2 + skb;
      char* lb = (char*)&Bs[buf][0][0] + q * 4096 + w * 1024;  // wave-uniform
      __builtin_amdgcn_global_load_lds(
          (const __attribute__((address_space(1))) void*)gb,
          (__attribute__((address_space(3))) void*)lb, 16, 0, 0);
    }
  };

  STAGE(0, 0);
  __syncthreads();  // drains vmcnt -> buf0 ready

  int cur = 0;
#pragma unroll
  for (int t = 0; t < 8; ++t) {
    if (t < 7) STAGE(cur ^ 1, (t + 1) * 64);  // prefetch next tile (in flight during compute)
#pragma unroll
    for (int ks = 0; ks < 2; ++ks) {
      int kb = ks * 32 + quad * 8;
      bf16x8 af[4], bfr[4];
#pragma unroll
      for (int i = 0; i < 4; ++i) af[i] = *(const bf16x8*)&As[cur][wm + i * 16 + m16][kb];
#pragma unroll
      for (int j = 0; j < 4; ++j) bfr[j] = *(const bf16x8*)&Bs[cur][wn + j * 16 + m16][kb];
#pragma unroll
      for (int i = 0; i < 4; ++i)
#pragma unroll
        for (int j = 0; j < 4; ++j)
          acc[i][j] = __builtin_amdgcn_mfma_f32_16x16x32_bf16(af[i], bfr[j], acc[i][j], 0, 0, 0);
    }
    __syncthreads();  // drains prefetch (hidden under the MFMAs above) + LDS reuse safety
    cur ^= 1;
  }

  float bv[4];
#pragma unroll
  for (int j = 0; j < 4; ++j) bv[j] = bias[bn + wn + j * 16 + m16];

  unsigned short* Ybs = (unsigned short*)Yb;
#pragma unroll
  for (int i = 0; i < 4; ++i) {
#pragma unroll
    for (int r = 0; r < 4; ++r) {
      int row = bm + wm + i * 16 + quad * 4 + r;
      if (row < M) {
        if (MODE == 0) {
          float nv = nvec[row];
#pragma unroll
          for (int j = 0; j < 4; ++j) {
            int c = bn + wn + j * 16 + m16;
            float a0 = acc[i][j][r] + bv[j];
            out[(size_t)row * 1024 + 512 + c] = a0;
            out[(size_t)row * 1024 + c] = a0 * nv;
          }
        } else {
#pragma unroll
          for (int j = 0; j < 4; ++j) {
            int c = bn + wn + j * 16 + m16;
            Ybs[(size_t)row * DD + c] = f2bf(acc[i][j][r] + bv[j]);
          }
        }
      }
    }
  }
}

// ---------------- SpMM (CSR, bf16 H): row r, 256 thr, 2 dims/thread ----------------
// (round-0 structure: measured floor 227us; rounds 1/3/4/5 proved slicing, MLP,
// nt-hints, and bucket-sort all fail to beat it -> L2-miss service bound.)
// MODE 0: Xb[r*512+d] = bf16(acc)
// MODE 1: Xb[r*512+d] = bf16(a1[r*1024+d] + acc*(1-n[r]))
// MODE 2: outF[r*1024+d] = acc (fp32)
template <int MODE>
__global__ __launch_bounds__(256) void spmm_bf16(
    const int* __restrict__ offs, const int* __restrict__ cols,
    const unsigned short* __restrict__ vals,
    const __bf16* __restrict__ H,
    __bf16* __restrict__ Xb, float* __restrict__ outF,
    const float* __restrict__ a1, const float* __restrict__ nvec) {
  int r = blockIdx.x;
  int t = threadIdx.x;
  int s = offs[r], e = offs[r + 1];
  int d = t * 2;
  float acc0 = 0.f, acc1 = 0.f;
  int i = s;
  for (; i + 4 <= e; i += 4) {
    int c0 = cols[i], c1 = cols[i + 1], c2 = cols[i + 2], c3 = cols[i + 3];
    float v0 = bfbits2f(vals[i]);
    float v1 = bfbits2f(vals[i + 1]);
    float v2 = bfbits2f(vals[i + 2]);
    float v3 = bfbits2f(vals[i + 3]);
    uint32_t h0 = *(const uint32_t*)(H + (size_t)c0 * DD + d);
    uint32_t h1 = *(const uint32_t*)(H + (size_t)c1 * DD + d);
    uint32_t h2 = *(const uint32_t*)(H + (size_t)c2 * DD + d);
    uint32_t h3 = *(const uint32_t*)(H + (size_t)c3 * DD + d);
    acc0 += v0 * bfbits2f(h0 & 0xffffu) + v1 * bfbits2f(h1 & 0xffffu) +
            v2 * bfbits2f(h2 & 0xffffu) + v3 * bfbits2f(h3 & 0xffffu);
    acc1 += v0 * bfbits2f(h0 >> 16) + v1 * bfbits2f(h1 >> 16) +
            v2 * bfbits2f(h2 >> 16) + v3 * bfbits2f(h3 >> 16);
  }
  for (; i < e; ++i) {
    int c = cols[i];
    float v = bfbits2f(vals[i]);
    uint32_t h = *(const uint32_t*)(H + (size_t)c * DD + d);
    acc0 += v * bfbits2f(h & 0xffffu);
    acc1 += v * bfbits2f(h >> 16);
  }
  if (MODE == 2) {
    float2 o;
    o.x = acc0;
    o.y = acc1;
    *(float2*)(outF + (size_t)r * 1024 + d) = o;
  } else {
    if (MODE == 1) {
      float g = 1.f - nvec[r];
      float2 a = *(const float2*)(a1 + (size_t)r * 1024 + d);
      acc0 = a.x + acc0 * g;
      acc1 = a.y + acc1 * g;
    }
    uint32_t p = ((uint32_t)f2bf(acc1) << 16) | (uint32_t)f2bf(acc0);
    *(uint32_t*)((unsigned short*)Xb + (size_t)r * DD + d) = p;
  }
}

extern "C" void kernel_launch(void* const* d_in, const int* in_sizes, int n_in,
                              void* d_out, int out_size, void* d_ws, size_t ws_size,
                              hipStream_t stream) {
  const float* A1       = (const float*)d_in[0];
  const int*   adj_rows = (const int*)d_in[1];
  const int*   adj_cols = (const int*)d_in[2];
  const float* adj_vals = (const float*)d_in[3];
  const float* Lin1     = (const float*)d_in[4];
  const float* Lin1b    = (const float*)d_in[5];
  const float* nvec     = (const float*)d_in[6];
  const float* W1       = (const float*)d_in[7];
  const float* b1       = (const float*)d_in[8];
  const float* W2       = (const float*)d_in[9];
  const float* b2       = (const float*)d_in[10];
  const float* W3       = (const float*)d_in[11];
  const float* b3       = (const float*)d_in[12];
  const int N = in_sizes[6];
  const int E = in_sizes[1];
  float* out = (float*)d_out;

  uint8_t* base = (uint8_t*)d_ws;
  size_t off = 0;
  auto take = [&](size_t bytes) -> void* {
    off = (off + 255) & ~(size_t)255;
    void* r = base + off;
    off += bytes;
    return r;
  };
  __bf16* Xb     = (__bf16*)take((size_t)N * DD * 2);       // 51.2 MB (x -> x1 -> s2)
  __bf16* Yb     = (__bf16*)take((size_t)N * DD * 2);       // 51.2 MB (GEMM outs)
  __bf16* Wt     = (__bf16*)take((size_t)4 * DD * DD * 2);  // 2 MB (transposed weights)
  int*    colsC  = (int*)take((size_t)E * sizeof(int));
  unsigned short* valsC = (unsigned short*)take((size_t)E * 2);
  int*    offs   = (int*)take((size_t)(N + 1) * sizeof(int));
  int*    counts = (int*)take((size_t)N * sizeof(int));     // reused as cursor
  int*    bsum   = (int*)take(1024);
  (void)ws_size; (void)n_in; (void)out_size;

  __bf16* Wt0 = Wt;
  __bf16* Wt1 = Wt + (size_t)DD * DD;
  __bf16* Wt2 = Wt + (size_t)2 * DD * DD;
  __bf16* Wt3 = Wt + (size_t)3 * DD * DD;

  int eb = (E + 255) / 256;
  int nb = (N + 255) / 256;

  // CSR build
  hipMemsetAsync(counts, 0, (size_t)N * sizeof(int), stream);
  hist_kernel<<<eb, 256, 0, stream>>>(adj_rows, counts, E);
  scan_block<<<nb, 256, 0, stream>>>(counts, offs, bsum, N);
  scan_tops<<<1, 256, 0, stream>>>(bsum, nb);
  scan_add<<<nb, 256, 0, stream>>>(offs, bsum, N);
  hipMemsetAsync(counts, 0, (size_t)N * sizeof(int), stream);  // cursor
  scatter_kernel<<<eb, 256, 0, stream>>>(adj_rows, adj_cols, adj_vals, offs, counts,
                                         colsC, valsC, E);

  // conversions
  convert_x<<<(N * DD / 8 + 255) / 256, 256, 0, stream>>>(A1, Xb, N);
  dim3 wgrid(16, 16);
  convert_wt<<<wgrid, 256, 0, stream>>>(Lin1, Wt0);
  convert_wt<<<wgrid, 256, 0, stream>>>(W1, Wt1);
  convert_wt<<<wgrid, 256, 0, stream>>>(W2, Wt2);
  convert_wt<<<wgrid, 256, 0, stream>>>(W3, Wt3);

  int ggrid = ((N + 127) / 128) * 4;  // 1D, 4 N-panels innermost

  // GEMM0: a0 -> out[:,512:] fp32; a1 = a0*n -> out[:,0:512] fp32
  gemm_mfma<0><<<ggrid, 256, 0, stream>>>(Xb, Wt0, Lin1b, nullptr, out, nvec, N);
  // GEMM1: y1 -> Yb
  gemm_mfma<1><<<ggrid, 256, 0, stream>>>(Xb, Wt1, b1, Yb, nullptr, nullptr, N);
  // SpMM1: x1 = a1 + spmm(y1)*(1-n) -> Xb (bf16)
  spmm_bf16<1><<<N, 256, 0, stream>>>(offs, colsC, valsC, Yb, Xb, nullptr, out, nvec);
  // GEMM2: y2 -> Yb
  gemm_mfma<1><<<ggrid, 256, 0, stream>>>(Xb, Wt2, b2, Yb, nullptr, nullptr, N);
  // SpMM2: s2 -> Xb (bf16)
  spmm_bf16<0><<<N, 256, 0, stream>>>(offs, colsC, valsC, Yb, Xb, nullptr, nullptr, nullptr);
  // GEMM3: y3 -> Yb
  gemm_mfma<1><<<ggrid, 256, 0, stream>>>(Xb, Wt3, b3, Yb, nullptr, nullptr, N);
  // SpMM3: x2 -> out[:,0:512] fp32
  spmm_bf16<2><<<N, 256, 0, stream>>>(offs, colsC, valsC, Yb, nullptr, out, nullptr, nullptr);
}

// Round 7
// 1352.666 us; speedup vs baseline: 1.0421x; 1.0079x over previous
//
#include <hip/hip_runtime.h>
#include <stdint.h>

#define DD 512

typedef __bf16 bf16x8 __attribute__((ext_vector_type(8)));
typedef float f32x4 __attribute__((ext_vector_type(4)));

__device__ __forceinline__ unsigned short f2bf(float f) {
  uint32_t u = __builtin_bit_cast(uint32_t, f);
  u += 0x7fff + ((u >> 16) & 1);  // RNE
  return (unsigned short)(u >> 16);
}
__device__ __forceinline__ float bfbits2f(uint32_t lo16) {
  return __builtin_bit_cast(float, lo16 << 16);
}

// ---------------- CSR build ----------------
__global__ void hist_kernel(const int* __restrict__ rows, int* __restrict__ counts, int E) {
  int i = blockIdx.x * blockDim.x + threadIdx.x;
  if (i < E) atomicAdd(&counts[rows[i]], 1);
}

__global__ __launch_bounds__(256) void scan_block(const int* __restrict__ counts,
                                                  int* __restrict__ offs, int* __restrict__ bsum,
                                                  int n) {
  __shared__ int sm[256];
  int t = threadIdx.x;
  int i = blockIdx.x * 256 + t;
  int v = (i < n) ? counts[i] : 0;
  sm[t] = v;
  __syncthreads();
  for (int o = 1; o < 256; o <<= 1) {
    int x = (t >= o) ? sm[t - o] : 0;
    __syncthreads();
    sm[t] += x;
    __syncthreads();
  }
  if (i < n) offs[i + 1] = sm[t];
  if (t == 255) bsum[blockIdx.x] = sm[255];
}

__global__ __launch_bounds__(256) void scan_tops(int* __restrict__ bsum, int nb) {
  __shared__ int sm[256];
  int t = threadIdx.x;
  int v = (t < nb) ? bsum[t] : 0;
  sm[t] = v;
  __syncthreads();
  for (int o = 1; o < 256; o <<= 1) {
    int x = (t >= o) ? sm[t - o] : 0;
    __syncthreads();
    sm[t] += x;
    __syncthreads();
  }
  if (t < nb) bsum[t] = sm[t];
}

__global__ __launch_bounds__(256) void scan_add(int* __restrict__ offs,
                                                const int* __restrict__ bsum, int n) {
  int i = blockIdx.x * 256 + threadIdx.x;
  int add = (blockIdx.x > 0) ? bsum[blockIdx.x - 1] : 0;
  if (i < n) offs[i + 1] += add;
  if (i == 0) offs[0] = 0;
}

__global__ void scatter_kernel(const int* __restrict__ rows, const int* __restrict__ colsIn,
                               const float* __restrict__ valsIn, const int* __restrict__ offs,
                               int* __restrict__ cursor, int* __restrict__ colsC,
                               unsigned short* __restrict__ valsC, int E) {
  int i = blockIdx.x * blockDim.x + threadIdx.x;
  if (i < E) {
    int r = rows[i];
    int p = offs[r] + atomicAdd(&cursor[r], 1);
    colsC[p] = colsIn[i];
    valsC[p] = f2bf(valsIn[i]);
  }
}

// ---------------- conversions ----------------
// x = A1[:,1:] (lda=513, +1 offset, unaligned) -> Xb bf16 [N][512]
__global__ __launch_bounds__(256) void convert_x(const float* __restrict__ A1,
                                                 __bf16* __restrict__ Xb, int N) {
  int id = blockIdx.x * 256 + threadIdx.x;  // one per 8 elements
  int total = (N * DD) >> 3;
  if (id >= total) return;
  int r = id >> 6;
  int c = (id & 63) * 8;
  const float* p = A1 + (size_t)r * 513 + 1 + c;
  unsigned short h[8];
#pragma unroll
  for (int k = 0; k < 8; ++k) h[k] = f2bf(p[k]);
  uint4 o;
  o.x = (uint32_t)h[0] | ((uint32_t)h[1] << 16);
  o.y = (uint32_t)h[2] | ((uint32_t)h[3] << 16);
  o.z = (uint32_t)h[4] | ((uint32_t)h[5] << 16);
  o.w = (uint32_t)h[6] | ((uint32_t)h[7] << 16);
  *(uint4*)(Xb + (size_t)r * DD + c) = o;
}

// W fp32 [k][n] -> Wt bf16 [n][k]  (transpose + convert)
__global__ __launch_bounds__(256) void convert_wt(const float* __restrict__ W,
                                                  __bf16* __restrict__ Wt) {
  __shared__ float tile[32][33];
  int bx = blockIdx.x * 32;  // n base
  int by = blockIdx.y * 32;  // k base
  int tx = threadIdx.x & 31, ty = threadIdx.x >> 5;  // ty 0..7
#pragma unroll
  for (int q = 0; q < 4; ++q)
    tile[ty + q * 8][tx] = W[(size_t)(by + ty + q * 8) * DD + bx + tx];
  __syncthreads();
  unsigned short* Wts = (unsigned short*)Wt;
#pragma unroll
  for (int q = 0; q < 4; ++q)
    Wts[(size_t)(bx + ty + q * 8) * DD + by + tx] = f2bf(tile[tx][ty + q * 8]);
}

// ---------------- MFMA GEMM ----------------
// A bf16 [M][512]; Bt bf16 [n][k] (transposed weights, stacked for MODE 2).
// 128x128 tile, 256 thr = 4 waves (2x2 of 64x64), BK=64, mfma_f32_16x16x32_bf16.
// Double-buffered global_load_lds staging (linear LDS, wave-uniform dest).
// MODE 1: 4 N-panels over Bt[512][512]:  Yb[r*512+c] = bf16(acc + bias[c])
// MODE 2: FUSED first layer, 8 N-panels over stacked Bt[1024][512] (Wt0|Wt1):
//         c<512 : a0 = acc + bias[c]  -> out[r*1024+512+c] (fp32, required output)
//                 a1 = a0 * n[r]      -> a1b[r*512+c] (bf16 side buffer)
//         c>=512: y1 = acc + bias2[c-512] -> Yb[r*512+(c-512)]
//         One pass over A for both layer-0 GEMMs; delta vs round 6 measures
//         the true cost of a GEMM pass (pre-committed diagnostic).
template <int MODE>
__global__ __launch_bounds__(256) void gemm_mfma(
    const __bf16* __restrict__ A,
    const __bf16* __restrict__ Bt,
    const float* __restrict__ bias,
    const float* __restrict__ bias2,
    __bf16* __restrict__ Yb,
    float* __restrict__ out,
    __bf16* __restrict__ a1b,
    const float* __restrict__ nvec,
    int M) {
  __shared__ __bf16 As[2][128][64];  // linear: 128B row stride (gld_lds dest)
  __shared__ __bf16 Bs[2][128][64];
  const int tid = threadIdx.x;
  const int NPSH = (MODE == 2) ? 3 : 2;          // N-panels: 8 or 4
  const int bx = blockIdx.x >> NPSH;             // M-panel
  const int by = blockIdx.x & ((1 << NPSH) - 1); // N-panel (innermost -> A reuse)
  const int bm = bx * 128;
  const int bn = by * 128;
  const int lane = tid & 63;
  const int w = tid >> 6;
  const int wm = (w & 1) * 64;
  const int wn = (w >> 1) * 64;
  const int m16 = lane & 15;
  const int quad = lane >> 4;

  f32x4 acc[4][4];
#pragma unroll
  for (int i = 0; i < 4; ++i)
#pragma unroll
    for (int j = 0; j < 4; ++j) acc[i][j] = (f32x4){0.f, 0.f, 0.f, 0.f};

  // staging geometry: thread t stages LDS bytes [t*16, t*16+16) of each 4KB
  // chunk; LDS dest is the wave-uniform base (HW adds lane*16).
  const int soff = tid * 16;
  const int srow_base = soff >> 7;      // row within 32-row chunk
  const int skb = soff & 127;           // byte within 128B row

  auto STAGE = [&](int buf, int k0) {
#pragma unroll
    for (int q = 0; q < 4; ++q) {
      int row = q * 32 + srow_base;
      int gm = bm + row;
      if (gm >= M) gm = M - 1;  // clamp (stores guarded)
      const char* ga = (const char*)A + ((size_t)gm * DD + k0) * 2 + skb;
      char* la = (char*)&As[buf][0][0] + q * 4096 + w * 1024;  // wave-uniform
      __builtin_amdgcn_global_load_lds(
          (const __attribute__((address_space(1))) void*)ga,
          (__attribute__((address_space(3))) void*)la, 16, 0, 0);
      const char* gb = (const char*)Bt + ((size_t)(bn + row) * DD + k0) * 2 + skb;
      char* lb = (char*)&Bs[buf][0][0] + q * 4096 + w * 1024;  // wave-uniform
      __builtin_amdgcn_global_load_lds(
          (const __attribute__((address_space(1))) void*)gb,
          (__attribute__((address_space(3))) void*)lb, 16, 0, 0);
    }
  };

  STAGE(0, 0);
  __syncthreads();

  int cur = 0;
#pragma unroll
  for (int t = 0; t < 8; ++t) {
    if (t < 7) STAGE(cur ^ 1, (t + 1) * 64);
#pragma unroll
    for (int ks = 0; ks < 2; ++ks) {
      int kb = ks * 32 + quad * 8;
      bf16x8 af[4], bfr[4];
#pragma unroll
      for (int i = 0; i < 4; ++i) af[i] = *(const bf16x8*)&As[cur][wm + i * 16 + m16][kb];
#pragma unroll
      for (int j = 0; j < 4; ++j) bfr[j] = *(const bf16x8*)&Bs[cur][wn + j * 16 + m16][kb];
#pragma unroll
      for (int i = 0; i < 4; ++i)
#pragma unroll
        for (int j = 0; j < 4; ++j)
          acc[i][j] = __builtin_amdgcn_mfma_f32_16x16x32_bf16(af[i], bfr[j], acc[i][j], 0, 0, 0);
    }
    __syncthreads();
    cur ^= 1;
  }

  const bool firstHalf = (MODE != 2) || (bn < 512);  // block-uniform
  float bv[4];
#pragma unroll
  for (int j = 0; j < 4; ++j) {
    int c = bn + wn + j * 16 + m16;
    bv[j] = firstHalf ? bias[c] : bias2[c - 512];
  }

  unsigned short* Ybs = (unsigned short*)Yb;
  unsigned short* a1s = (unsigned short*)a1b;
#pragma unroll
  for (int i = 0; i < 4; ++i) {
#pragma unroll
    for (int r = 0; r < 4; ++r) {
      int row = bm + wm + i * 16 + quad * 4 + r;
      if (row < M) {
        if (MODE == 2 && firstHalf) {
          float nv = nvec[row];
#pragma unroll
          for (int j = 0; j < 4; ++j) {
            int c = bn + wn + j * 16 + m16;
            float a0 = acc[i][j][r] + bv[j];
            out[(size_t)row * 1024 + 512 + c] = a0;
            a1s[(size_t)row * DD + c] = f2bf(a0 * nv);
          }
        } else {
#pragma unroll
          for (int j = 0; j < 4; ++j) {
            int c = bn + wn + j * 16 + m16;
            int cc = (MODE == 2) ? c - 512 : c;
            Ybs[(size_t)row * DD + cc] = f2bf(acc[i][j][r] + bv[j]);
          }
        }
      }
    }
  }
}

// ---------------- SpMM (CSR, bf16 H): row r, 256 thr, 2 dims/thread ----------------
// (round-0 structure: measured floor 227us; rounds 1/3/4/5 proved slicing, MLP,
// nt-hints, and bucket-sort all fail to beat it -> scattered-access service bound.)
// MODE 0: Xb[r*512+d] = bf16(acc)
// MODE 1: Xb[r*512+d] = bf16(a1b[r*512+d] + acc*(1-n[r]))   (a1b is bf16 now)
// MODE 2: outF[r*1024+d] = acc (fp32)
template <int MODE>
__global__ __launch_bounds__(256) void spmm_bf16(
    const int* __restrict__ offs, const int* __restrict__ cols,
    const unsigned short* __restrict__ vals,
    const __bf16* __restrict__ H,
    __bf16* __restrict__ Xb, float* __restrict__ outF,
    const __bf16* __restrict__ a1b, const float* __restrict__ nvec) {
  int r = blockIdx.x;
  int t = threadIdx.x;
  int s = offs[r], e = offs[r + 1];
  int d = t * 2;
  float acc0 = 0.f, acc1 = 0.f;
  int i = s;
  for (; i + 4 <= e; i += 4) {
    int c0 = cols[i], c1 = cols[i + 1], c2 = cols[i + 2], c3 = cols[i + 3];
    float v0 = bfbits2f(vals[i]);
    float v1 = bfbits2f(vals[i + 1]);
    float v2 = bfbits2f(vals[i + 2]);
    float v3 = bfbits2f(vals[i + 3]);
    uint32_t h0 = *(const uint32_t*)(H + (size_t)c0 * DD + d);
    uint32_t h1 = *(const uint32_t*)(H + (size_t)c1 * DD + d);
    uint32_t h2 = *(const uint32_t*)(H + (size_t)c2 * DD + d);
    uint32_t h3 = *(const uint32_t*)(H + (size_t)c3 * DD + d);
    acc0 += v0 * bfbits2f(h0 & 0xffffu) + v1 * bfbits2f(h1 & 0xffffu) +
            v2 * bfbits2f(h2 & 0xffffu) + v3 * bfbits2f(h3 & 0xffffu);
    acc1 += v0 * bfbits2f(h0 >> 16) + v1 * bfbits2f(h1 >> 16) +
            v2 * bfbits2f(h2 >> 16) + v3 * bfbits2f(h3 >> 16);
  }
  for (; i < e; ++i) {
    int c = cols[i];
    float v = bfbits2f(vals[i]);
    uint32_t h = *(const uint32_t*)(H + (size_t)c * DD + d);
    acc0 += v * bfbits2f(h & 0xffffu);
    acc1 += v * bfbits2f(h >> 16);
  }
  if (MODE == 2) {
    float2 o;
    o.x = acc0;
    o.y = acc1;
    *(float2*)(outF + (size_t)r * 1024 + d) = o;
  } else {
    if (MODE == 1) {
      float g = 1.f - nvec[r];
      uint32_t aw = *(const uint32_t*)((const unsigned short*)a1b + (size_t)r * DD + d);
      acc0 = bfbits2f(aw & 0xffffu) + acc0 * g;
      acc1 = bfbits2f(aw >> 16) + acc1 * g;
    }
    uint32_t p = ((uint32_t)f2bf(acc1) << 16) | (uint32_t)f2bf(acc0);
    *(uint32_t*)((unsigned short*)Xb + (size_t)r * DD + d) = p;
  }
}

extern "C" void kernel_launch(void* const* d_in, const int* in_sizes, int n_in,
                              void* d_out, int out_size, void* d_ws, size_t ws_size,
                              hipStream_t stream) {
  const float* A1       = (const float*)d_in[0];
  const int*   adj_rows = (const int*)d_in[1];
  const int*   adj_cols = (const int*)d_in[2];
  const float* adj_vals = (const float*)d_in[3];
  const float* Lin1     = (const float*)d_in[4];
  const float* Lin1b    = (const float*)d_in[5];
  const float* nvec     = (const float*)d_in[6];
  const float* W1       = (const float*)d_in[7];
  const float* b1       = (const float*)d_in[8];
  const float* W2       = (const float*)d_in[9];
  const float* b2       = (const float*)d_in[10];
  const float* W3       = (const float*)d_in[11];
  const float* b3       = (const float*)d_in[12];
  const int N = in_sizes[6];
  const int E = in_sizes[1];
  float* out = (float*)d_out;

  uint8_t* base = (uint8_t*)d_ws;
  size_t off = 0;
  auto take = [&](size_t bytes) -> void* {
    off = (off + 255) & ~(size_t)255;
    void* r = base + off;
    off += bytes;
    return r;
  };
  __bf16* Xb     = (__bf16*)take((size_t)N * DD * 2);       // 51.2 MB (x -> x1 -> s2)
  __bf16* Yb     = (__bf16*)take((size_t)N * DD * 2);       // 51.2 MB (GEMM outs)
  __bf16* a1b    = (__bf16*)take((size_t)N * DD * 2);       // 51.2 MB (a1 bf16)
  __bf16* Wt     = (__bf16*)take((size_t)4 * DD * DD * 2);  // 2 MB (transposed weights)
  int*    colsC  = (int*)take((size_t)E * sizeof(int));
  unsigned short* valsC = (unsigned short*)take((size_t)E * 2);
  int*    offs   = (int*)take((size_t)(N + 1) * sizeof(int));
  int*    counts = (int*)take((size_t)N * sizeof(int));     // reused as cursor
  int*    bsum   = (int*)take(1024);
  (void)ws_size; (void)n_in; (void)out_size;

  __bf16* Wt0 = Wt;                                // [0..511]   : Lin1^T
  __bf16* Wt1 = Wt + (size_t)DD * DD;              // [512..1023]: W1^T (stacked after Wt0)
  __bf16* Wt2 = Wt + (size_t)2 * DD * DD;
  __bf16* Wt3 = Wt + (size_t)3 * DD * DD;

  int eb = (E + 255) / 256;
  int nb = (N + 255) / 256;

  // CSR build
  hipMemsetAsync(counts, 0, (size_t)N * sizeof(int), stream);
  hist_kernel<<<eb, 256, 0, stream>>>(adj_rows, counts, E);
  scan_block<<<nb, 256, 0, stream>>>(counts, offs, bsum, N);
  scan_tops<<<1, 256, 0, stream>>>(bsum, nb);
  scan_add<<<nb, 256, 0, stream>>>(offs, bsum, N);
  hipMemsetAsync(counts, 0, (size_t)N * sizeof(int), stream);  // cursor
  scatter_kernel<<<eb, 256, 0, stream>>>(adj_rows, adj_cols, adj_vals, offs, counts,
                                         colsC, valsC, E);

  // conversions
  convert_x<<<(N * DD / 8 + 255) / 256, 256, 0, stream>>>(A1, Xb, N);
  dim3 wgrid(16, 16);
  convert_wt<<<wgrid, 256, 0, stream>>>(Lin1, Wt0);
  convert_wt<<<wgrid, 256, 0, stream>>>(W1, Wt1);
  convert_wt<<<wgrid, 256, 0, stream>>>(W2, Wt2);
  convert_wt<<<wgrid, 256, 0, stream>>>(W3, Wt3);

  int mp = (N + 127) / 128;

  // Fused GEMM0+GEMM1 over stacked Bt[1024][512] = [Wt0; Wt1]:
  //   a0 -> out[:,512:], a1 -> a1b (bf16), y1 -> Yb   -- one pass over Xb
  gemm_mfma<2><<<mp * 8, 256, 0, stream>>>(Xb, Wt0, Lin1b, b1, Yb, out, a1b, nvec, N);
  // SpMM1: x1 = a1 + spmm(y1)*(1-n) -> Xb (bf16)
  spmm_bf16<1><<<N, 256, 0, stream>>>(offs, colsC, valsC, Yb, Xb, nullptr, a1b, nvec);
  // GEMM2: y2 -> Yb
  gemm_mfma<1><<<mp * 4, 256, 0, stream>>>(Xb, Wt2, b2, nullptr, Yb, nullptr, nullptr, nullptr, N);
  // SpMM2: s2 -> Xb (bf16)
  spmm_bf16<0><<<N, 256, 0, stream>>>(offs, colsC, valsC, Yb, Xb, nullptr, nullptr, nullptr);
  // GEMM3: y3 -> Yb
  gemm_mfma<1><<<mp * 4, 256, 0, stream>>>(Xb, Wt3, b3, nullptr, Yb, nullptr, nullptr, nullptr, N);
  // SpMM3: x2 -> out[:,0:512] fp32
  spmm_bf16<2><<<N, 256, 0, stream>>>(offs, colsC, valsC, Yb, nullptr, out, nullptr, nullptr);
}